// Round 1
// 683.206 us; speedup vs baseline: 1.0475x; 1.0475x over previous
//
#include <hip/hip_runtime.h>
#include <stdint.h>

typedef short bf16x8 __attribute__((ext_vector_type(8)));
typedef float f32x4  __attribute__((ext_vector_type(4)));

constexpr int BT = 4096;   // tokens
constexpr int DD = 1024;   // model dim
constexpr int OO = 1024;   // output dim
constexpr int EE = 8;      // experts
constexpr int HH = 4096;   // hidden dim
constexpr int SLOTS = 2 * BT;  // 8192

// ---- pipelined-GEMM geometry ----
constexpr int BM = 256, BN = 128, BK = 32;
constexpr int RING = 4;                    // 4-slot LDS ring
constexpr int A_USH = BM * BK;             // 8192 ushorts (16 KB)
constexpr int TILE_USH = (BM + BN) * BK;   // 12288 ushorts (24 KB)
constexpr int MAXT = 40;                   // max 256-row m-tiles

__device__ __forceinline__ unsigned short f2bf(float f) {
  unsigned u = __float_as_uint(f);
  u += 0x7fffu + ((u >> 16) & 1u);   // round-to-nearest-even
  return (unsigned short)(u >> 16);
}

// async 16B global->LDS. LDS dest is wave-uniform base; HW adds lane*16.
__device__ __forceinline__ void glds16(const unsigned short* g, unsigned short* l) {
  __builtin_amdgcn_global_load_lds(
      (const __attribute__((address_space(1))) void*)g,
      (__attribute__((address_space(3))) void*)l, 16, 0, 0);
}

// ---------- router: logits, top-2 softmax, expert lists; also x -> bf16 ----------
__global__ __launch_bounds__(256) void router_k(const float* __restrict__ x,
                                                const float* __restrict__ gw,
                                                const float* __restrict__ gb,
                                                unsigned short* __restrict__ xb,
                                                int* __restrict__ cnt,
                                                int* __restrict__ list,
                                                float* __restrict__ rw) {
  int wave = threadIdx.x >> 6, lane = threadIdx.x & 63;
  int b = blockIdx.x * 4 + wave;
  const float* xrow = x + (size_t)b * DD;
  float acc[8];
#pragma unroll
  for (int e = 0; e < 8; ++e) acc[e] = 0.f;
#pragma unroll
  for (int i = 0; i < 4; ++i) {
    int d0 = i * 256 + lane * 4;
    float4 v = *(const float4*)&xrow[d0];
    unsigned lo = (unsigned)f2bf(v.x) | ((unsigned)f2bf(v.y) << 16);
    unsigned hi = (unsigned)f2bf(v.z) | ((unsigned)f2bf(v.w) << 16);
    *(uint2*)&xb[(size_t)b * DD + d0] = make_uint2(lo, hi);
    const float* g0 = &gw[(size_t)d0 * 8];
    float fv[4] = {v.x, v.y, v.z, v.w};
#pragma unroll
    for (int q = 0; q < 4; ++q) {
      float4 ga = *(const float4*)&g0[q * 8];
      float4 gc = *(const float4*)&g0[q * 8 + 4];
      acc[0] += fv[q] * ga.x; acc[1] += fv[q] * ga.y;
      acc[2] += fv[q] * ga.z; acc[3] += fv[q] * ga.w;
      acc[4] += fv[q] * gc.x; acc[5] += fv[q] * gc.y;
      acc[6] += fv[q] * gc.z; acc[7] += fv[q] * gc.w;
    }
  }
#pragma unroll
  for (int off = 32; off > 0; off >>= 1) {
#pragma unroll
    for (int e = 0; e < 8; ++e) acc[e] += __shfl_down(acc[e], off);
  }
  if (lane == 0) {
    float v[8];
#pragma unroll
    for (int e = 0; e < 8; ++e) v[e] = acc[e] + gb[e];
    int i0 = 0;
#pragma unroll
    for (int e = 1; e < 8; ++e) if (v[e] > v[i0]) i0 = e;
    int i1 = (i0 == 0) ? 1 : 0;
#pragma unroll
    for (int e = 0; e < 8; ++e) if (e != i0 && v[e] > v[i1]) i1 = e;
    float e1 = __expf(v[i1] - v[i0]);
    float inv = 1.0f / (1.0f + e1);
    int p0 = atomicAdd(&cnt[i0], 1);
    list[i0 * BT + p0] = 2 * b;     rw[2 * b]     = inv;
    int p1 = atomicAdd(&cnt[i1], 1);
    list[i1 * BT + p1] = 2 * b + 1; rw[2 * b + 1] = e1 * inv;
  }
}

// ---- tile map: (expert, m0, compacted_base) per 256-row tile; ntiles <= 40 ----
__global__ void tilemap_k(const int* __restrict__ cnt, int* __restrict__ tmap,
                          int* __restrict__ ntiles) {
  if (threadIdx.x == 0 && blockIdx.x == 0) {
    int t = 0, basewalk = 0;
    for (int e = 0; e < EE; ++e) {
      int c = cnt[e];
      for (int m0 = 0; m0 < c; m0 += BM) {
        tmap[4 * t] = e; tmap[4 * t + 1] = m0; tmap[4 * t + 2] = basewalk + m0; ++t;
      }
      basewalk += c;
    }
    *ntiles = t;
  }
}

// ------- transpose+convert: src fp32 [E][R][C] -> dst bf16 [E][C][R] -------
__global__ __launch_bounds__(256) void cvt_t_k(const float* __restrict__ src,
                                               unsigned short* __restrict__ dst,
                                               int R, int C) {
  __shared__ unsigned short tile[64][66];
  int e = blockIdx.z;
  const float* s = src + (size_t)e * R * C;
  unsigned short* d = dst + (size_t)e * R * C;
  int r0 = blockIdx.x << 6, c0 = blockIdx.y << 6;
  int t = threadIdx.x;
#pragma unroll
  for (int p = 0; p < 4; ++p) {
    int ch = p * 256 + t;
    int rr = ch >> 4, cc = (ch & 15) << 2;
    float4 v = *(const float4*)&s[(size_t)(r0 + rr) * C + c0 + cc];
    unsigned lo = (unsigned)f2bf(v.x) | ((unsigned)f2bf(v.y) << 16);
    unsigned hi = (unsigned)f2bf(v.z) | ((unsigned)f2bf(v.w) << 16);
    *(uint2*)&tile[rr][cc] = make_uint2(lo, hi);
  }
  __syncthreads();
#pragma unroll
  for (int p = 0; p < 4; ++p) {
    int ch = p * 256 + t;
    int cc = ch >> 4, rr = (ch & 15) << 2;
    unsigned short v0 = tile[rr + 0][cc];
    unsigned short v1 = tile[rr + 1][cc];
    unsigned short v2 = tile[rr + 2][cc];
    unsigned short v3 = tile[rr + 3][cc];
    unsigned lo = (unsigned)v0 | ((unsigned)v1 << 16);
    unsigned hi = (unsigned)v2 | ((unsigned)v3 << 16);
    *(uint2*)&d[(size_t)(c0 + cc) * R + r0 + rr] = make_uint2(lo, hi);
  }
}

// =====================================================================
// GEMM1: hc[base+row] = relu(x[tok] @ w1[e] + b1[e]), compacted layout.
// 256x128 tile, BK=32, ring-4 LDS pipeline, counted vmcnt, setprio.
// grid: (HH/BN = 32, 40); 512 threads = 8 waves (4M x 2N), wave C = 64x64.
// =====================================================================
__global__ __launch_bounds__(512, 2) void gemm1_k(const unsigned short* __restrict__ xb,
                                                  const unsigned short* __restrict__ w1t,
                                                  const float* __restrict__ b1,
                                                  const int* __restrict__ cnt,
                                                  const int* __restrict__ list,
                                                  const int* __restrict__ tmap,
                                                  const int* __restrict__ ntiles,
                                                  unsigned short* __restrict__ hc) {
  int ti = blockIdx.y;
  if (ti >= *ntiles) return;
  int e = tmap[4 * ti], m0 = tmap[4 * ti + 1], base = tmap[4 * ti + 2];
  int cnt_e = cnt[e];
  int n0 = blockIdx.x * BN;

  __shared__ int slotbuf[BM];
  __shared__ __align__(16) unsigned short lds[RING * TILE_USH];  // 96 KB

  int t = threadIdx.x;
  if (t < BM) {
    int r = m0 + t;
    slotbuf[t] = list[e * BT + (r < cnt_e ? r : 0)];
  }
  __syncthreads();

  int w = t >> 6, l = t & 63, lm = l & 15, lq = l >> 4;
  int wr = w >> 1, wc = w & 1;

  // ---- staging sources: 3 x 16B per thread per K-tile (A 2 rows-halves, B 1) ----
  int rstage = t >> 2;           // 0..127
  int ch8 = (t & 3) * 8;         // ushort offset of 16B chunk within 32-elem row
  const unsigned short* aS0 = xb + (size_t)(slotbuf[rstage] >> 1) * DD + ch8;
  const unsigned short* aS1 = xb + (size_t)(slotbuf[128 + rstage] >> 1) * DD + ch8;
  const unsigned short* bS  = w1t + (size_t)e * HH * DD + (size_t)(n0 + rstage) * DD + ch8;
  // wave-uniform LDS dest offsets (ushort units); HW adds lane*16B
  int dA0 = w * 512, dA1 = 4096 + w * 512, dB = A_USH + w * 512;

  // fragment offsets (BK=32 -> 64B rows -> conflict-free b128 reads, no swizzle)
  int afo[4], bfo[4];
#pragma unroll
  for (int mi = 0; mi < 4; ++mi) afo[mi] = (wr * 64 + mi * 16 + lm) * BK + lq * 8;
#pragma unroll
  for (int ni = 0; ni < 4; ++ni) bfo[ni] = A_USH + (wc * 64 + ni * 16 + lm) * BK + lq * 8;

  f32x4 acc[4][4];
#pragma unroll
  for (int mi = 0; mi < 4; ++mi)
#pragma unroll
    for (int ni = 0; ni < 4; ++ni) acc[mi][ni] = f32x4{0.f, 0.f, 0.f, 0.f};

  constexpr int NT = DD / BK;  // 32

  // prologue: stage tiles 0..2
#pragma unroll
  for (int p = 0; p < RING - 1; ++p) {
    unsigned short* Lb = lds + p * TILE_USH;
    glds16(aS0 + p * BK, Lb + dA0);
    glds16(aS1 + p * BK, Lb + dA1);
    glds16(bS  + p * BK, Lb + dB);
  }
  asm volatile("s_waitcnt vmcnt(6)" ::: "memory");  // tile 0 landed
  __builtin_amdgcn_s_barrier();
  asm volatile("" ::: "memory");

  for (int tt = 0; tt < NT; ++tt) {
    const unsigned short* Lc = lds + (tt & 3) * TILE_USH;
    bf16x8 af[4], bf[4];
#pragma unroll
    for (int mi = 0; mi < 4; ++mi) af[mi] = *(const bf16x8*)&Lc[afo[mi]];
#pragma unroll
    for (int ni = 0; ni < 4; ++ni) bf[ni] = *(const bf16x8*)&Lc[bfo[ni]];
    {  // stage tile tt+3 (branchless tail: clamped re-read into dead slot keeps vmcnt exact)
      int ts = tt + 3;
      int ko = (ts < NT ? ts : NT - 1) * BK;
      unsigned short* Lb = lds + (ts & 3) * TILE_USH;
      glds16(aS0 + ko, Lb + dA0);
      glds16(aS1 + ko, Lb + dA1);
      glds16(bS  + ko, Lb + dB);
    }
    __builtin_amdgcn_s_setprio(1);
#pragma unroll
    for (int mi = 0; mi < 4; ++mi)
#pragma unroll
      for (int ni = 0; ni < 4; ++ni)
        acc[mi][ni] = __builtin_amdgcn_mfma_f32_16x16x32_bf16(af[mi], bf[ni], acc[mi][ni], 0, 0, 0);
    __builtin_amdgcn_s_setprio(0);
    asm volatile("s_waitcnt vmcnt(6)" ::: "memory");  // tile tt+1 landed; 2 tiles stay in flight
    __builtin_amdgcn_s_barrier();
    asm volatile("" ::: "memory");
  }

  // ---- epilogue: drain in-flight loads, then LDS-transpose -> coalesced 16B stores ----
  asm volatile("s_waitcnt vmcnt(0)" ::: "memory");
  __builtin_amdgcn_s_barrier();
  asm volatile("" ::: "memory");
  unsigned short* cb = lds + w * 4096;  // 64x64 bf16 per wave (8 KB)
  float bias[4];
#pragma unroll
  for (int ni = 0; ni < 4; ++ni) bias[ni] = b1[e * HH + n0 + wc * 64 + ni * 16 + lm];
#pragma unroll
  for (int mi = 0; mi < 4; ++mi)
#pragma unroll
    for (int ni = 0; ni < 4; ++ni)
#pragma unroll
      for (int r = 0; r < 4; ++r)
        cb[(mi * 16 + lq * 4 + r) * 64 + ni * 16 + lm] =
            f2bf(fmaxf(acc[mi][ni][r] + bias[ni], 0.0f));
  asm volatile("s_waitcnt lgkmcnt(0)" ::: "memory");  // same-wave LDS write->read
#pragma unroll
  for (int it = 0; it < 8; ++it) {
    int rr = it * 8 + (l >> 3), chk = l & 7;
    int lrow = wr * 64 + rr;
    if (m0 + lrow < cnt_e) {
      uint4 v = *(const uint4*)&cb[rr * 64 + chk * 8];
      *(uint4*)&hc[(size_t)(base + lrow) * HH + n0 + wc * 64 + chk * 8] = v;
    }
  }
}

// =====================================================================
// GEMM2: y[z][slot] = rw*(hc_rows @ w2[e] + b2[e] [z==0]); same pipeline.
// grid: (OO/BN = 8, 40, zsplit)
// =====================================================================
__global__ __launch_bounds__(512, 2) void gemm2_k(const unsigned short* __restrict__ hc,
                                                  const unsigned short* __restrict__ w2t,
                                                  const float* __restrict__ b2,
                                                  const int* __restrict__ cnt,
                                                  const int* __restrict__ list,
                                                  const int* __restrict__ tmap,
                                                  const int* __restrict__ ntiles,
                                                  const float* __restrict__ rw,
                                                  float* __restrict__ ybuf,
                                                  float* __restrict__ out) {
  int ti = blockIdx.y;
  if (ti >= *ntiles) return;
  int e = tmap[4 * ti], m0 = tmap[4 * ti + 1], base = tmap[4 * ti + 2];
  int cnt_e = cnt[e];
  int n0 = blockIdx.x * BN;
  int z = blockIdx.z;
  int ksl = HH / gridDim.z;
  int kb0 = z * ksl;
  int NT = ksl / BK;

  __shared__ int slotbuf[BM];
  __shared__ float rwbuf[BM];
  __shared__ __align__(16) unsigned short lds[RING * TILE_USH];

  int t = threadIdx.x;
  if (t < BM) {
    int r = m0 + t;
    int s_ = list[e * BT + (r < cnt_e ? r : 0)];
    slotbuf[t] = s_;
    rwbuf[t] = rw[s_];
  }
  __syncthreads();

  int w = t >> 6, l = t & 63, lm = l & 15, lq = l >> 4;
  int wr = w >> 1, wc = w & 1;

  int rstage = t >> 2, ch8 = (t & 3) * 8;
  int gr0 = base + rstage;       if (gr0 > SLOTS - 1) gr0 = SLOTS - 1;  // clamp padded rows
  int gr1 = base + 128 + rstage; if (gr1 > SLOTS - 1) gr1 = SLOTS - 1;
  const unsigned short* aS0 = hc + (size_t)gr0 * HH + kb0 + ch8;
  const unsigned short* aS1 = hc + (size_t)gr1 * HH + kb0 + ch8;
  const unsigned short* bS  = w2t + (size_t)e * OO * HH + (size_t)(n0 + rstage) * HH + kb0 + ch8;
  int dA0 = w * 512, dA1 = 4096 + w * 512, dB = A_USH + w * 512;

  int afo[4], bfo[4];
#pragma unroll
  for (int mi = 0; mi < 4; ++mi) afo[mi] = (wr * 64 + mi * 16 + lm) * BK + lq * 8;
#pragma unroll
  for (int ni = 0; ni < 4; ++ni) bfo[ni] = A_USH + (wc * 64 + ni * 16 + lm) * BK + lq * 8;

  f32x4 acc[4][4];
#pragma unroll
  for (int mi = 0; mi < 4; ++mi)
#pragma unroll
    for (int ni = 0; ni < 4; ++ni) acc[mi][ni] = f32x4{0.f, 0.f, 0.f, 0.f};

#pragma unroll
  for (int p = 0; p < RING - 1; ++p) {
    unsigned short* Lb = lds + p * TILE_USH;
    glds16(aS0 + p * BK, Lb + dA0);
    glds16(aS1 + p * BK, Lb + dA1);
    glds16(bS  + p * BK, Lb + dB);
  }
  asm volatile("s_waitcnt vmcnt(6)" ::: "memory");
  __builtin_amdgcn_s_barrier();
  asm volatile("" ::: "memory");

  for (int tt = 0; tt < NT; ++tt) {
    const unsigned short* Lc = lds + (tt & 3) * TILE_USH;
    bf16x8 af[4], bf[4];
#pragma unroll
    for (int mi = 0; mi < 4; ++mi) af[mi] = *(const bf16x8*)&Lc[afo[mi]];
#pragma unroll
    for (int ni = 0; ni < 4; ++ni) bf[ni] = *(const bf16x8*)&Lc[bfo[ni]];
    {
      int ts = tt + 3;
      int ko = (ts < NT ? ts : NT - 1) * BK;
      unsigned short* Lb = lds + (ts & 3) * TILE_USH;
      glds16(aS0 + ko, Lb + dA0);
      glds16(aS1 + ko, Lb + dA1);
      glds16(bS  + ko, Lb + dB);
    }
    __builtin_amdgcn_s_setprio(1);
#pragma unroll
    for (int mi = 0; mi < 4; ++mi)
#pragma unroll
      for (int ni = 0; ni < 4; ++ni)
        acc[mi][ni] = __builtin_amdgcn_mfma_f32_16x16x32_bf16(af[mi], bf[ni], acc[mi][ni], 0, 0, 0);
    __builtin_amdgcn_s_setprio(0);
    asm volatile("s_waitcnt vmcnt(6)" ::: "memory");
    __builtin_amdgcn_s_barrier();
    asm volatile("" ::: "memory");
  }

  // ---- epilogue: fp32 stores (64B segments, low amplification) ----
  bool addb = (z == 0);
  size_t ybase = (size_t)z * SLOTS;
#pragma unroll
  for (int ni = 0; ni < 4; ++ni) {
    int ncol = n0 + wc * 64 + ni * 16 + lm;
    float bias = addb ? b2[e * OO + ncol] : 0.0f;
#pragma unroll
    for (int mi = 0; mi < 4; ++mi)
#pragma unroll
      for (int r = 0; r < 4; ++r) {
        int lrow = wr * 64 + mi * 16 + lq * 4 + r;
        if (m0 + lrow < cnt_e) {
          float v = (acc[mi][ni][r] + bias) * rwbuf[lrow];
          int slot = slotbuf[lrow];
          if (ybuf) ybuf[(ybase + slot) * OO + ncol] = v;
          else      atomicAdd(&out[(size_t)(slot >> 1) * OO + ncol], v);
        }
      }
  }
}

// ---- combine: out[b] = sum_z (y[z][2b] + y[z][2b+1]) ----
__global__ __launch_bounds__(256) void combine_k(const float* __restrict__ y,
                                                 float* __restrict__ out, int nz) {
  int i = blockIdx.x * 256 + threadIdx.x;        // one float4 of out
  int b = i >> 8, c = i & 255;                   // 256 float4 per row
  f32x4 acc = {0.f, 0.f, 0.f, 0.f};
  for (int z = 0; z < nz; ++z) {
#pragma unroll
    for (int k = 0; k < 2; ++k) {
      const float4 v = *(const float4*)&y[((size_t)z * SLOTS + 2 * b + k) * OO + c * 4];
      acc[0] += v.x; acc[1] += v.y; acc[2] += v.z; acc[3] += v.w;
    }
  }
  *(f32x4*)&out[(size_t)b * OO + c * 4] = acc;
}

extern "C" void kernel_launch(void* const* d_in, const int* in_sizes, int n_in,
                              void* d_out, int out_size, void* d_ws, size_t ws_size,
                              hipStream_t stream) {
  const float* x  = (const float*)d_in[0];
  const float* gw = (const float*)d_in[1];
  const float* gb = (const float*)d_in[2];
  const float* w1 = (const float*)d_in[3];
  const float* b1 = (const float*)d_in[4];
  const float* w2 = (const float*)d_in[5];
  const float* b2 = (const float*)d_in[6];
  float* out = (float*)d_out;
  char* ws = (char*)d_ws;

  // ws layout
  int*            cnt    = (int*)(ws);                          // 32 B
  int*            ntiles = (int*)(ws + 64);
  int*            tmap   = (int*)(ws + 128);                    // 40*16 B
  float*          rw     = (float*)(ws + 4096);                 // 32 KB
  int*            list   = (int*)(ws + (64u << 10));            // 128 KB
  unsigned short* xb     = (unsigned short*)(ws + (1u  << 20)); // 8 MB
  unsigned short* wt     = (unsigned short*)(ws + (9u  << 20)); // 64 MB (w1t, then w2t)
  unsigned short* hc     = (unsigned short*)(ws + (73u << 20)); // 64 MB + 1 MB slack
  float*          ybuf   = (float*)(ws + (138u << 20));         // up to 64 MB

  size_t need_min = (138u << 20);
  if (ws_size < need_min) return;
  int zsplit;
  float* ypass;
  if (ws_size >= (138u << 20) + (size_t)2 * SLOTS * OO * 4) { zsplit = 2; ypass = ybuf; }
  else if (ws_size >= (138u << 20) + (size_t)SLOTS * OO * 4) { zsplit = 1; ypass = ybuf; }
  else { zsplit = 2; ypass = nullptr; }

  hipMemsetAsync(cnt, 0, 64, stream);
  if (!ypass) hipMemsetAsync(out, 0, (size_t)BT * OO * sizeof(float), stream);

  router_k<<<BT / 4, 256, 0, stream>>>(x, gw, gb, xb, cnt, list, rw);
  tilemap_k<<<1, 64, 0, stream>>>(cnt, tmap, ntiles);
  cvt_t_k<<<dim3(DD / 64, HH / 64, EE), 256, 0, stream>>>(w1, wt, DD, HH);
  gemm1_k<<<dim3(HH / BN, MAXT), 512, 0, stream>>>(xb, wt, b1, cnt, list, tmap, ntiles, hc);
  cvt_t_k<<<dim3(HH / 64, OO / 64, EE), 256, 0, stream>>>(w2, wt, HH, OO);
  gemm2_k<<<dim3(OO / BN, MAXT, zsplit), 512, 0, stream>>>(hc, wt, b2, cnt, list, tmap, ntiles, rw, ypass, out);
  if (ypass)
    combine_k<<<BT * OO / 1024, 256, 0, stream>>>(ybuf, out, zsplit);
}